// Round 2
// baseline (153.383 us; speedup 1.0000x reference)
//
#include <hip/hip_runtime.h>

// B=256, A=128, D=5, FA=256, FB=64, C=256, F=320.
// mask=(deg==arange(5)): deg==5 (~96% of rows) -> zero row.
// Heavy rows (~1300, almost all deg=4) need relu(feat(320) @ W[deg](320x256)+b[deg]).
//
// Phase 0: memset ws counters.
// Phase 1: classify_zero — zero-fill out (float4 grid-stride) + append heavy
//          rows to per-deg worklists (atomics, ~1300 total).
// Phase 2: matvec — each block grabs a tile of 8 same-deg rows, builds feat
//          in LDS, then 256 threads (=channels) stream W[deg] ONCE for all
//          8 rows (W L2 traffic /8 vs one-row-per-block).

#define NB 256
#define NA 128
#define ND 5
#define NFA 256
#define NFB 64
#define NC 256
#define NF 320
#define NROWS (NB * NA)      // 32768
#define GROUP 8

__global__ __launch_bounds__(256) void classify_zero(
    const int* __restrict__ edges,   // NROWS*ND
    float4* __restrict__ out4,       // NROWS*NC/4 float4
    int* __restrict__ cnt,           // [8] counters (first 5 used)
    int* __restrict__ lists)         // [5][NROWS]
{
    const int tid = blockIdx.x * 256 + threadIdx.x;   // 0..65535 (256 blocks)
    const int total4 = NROWS * NC / 4;                // 2097152
    // zero-fill the whole output, coalesced float4, grid-stride
    for (int i = tid; i < total4; i += 256 * 256)
        out4[i] = make_float4(0.f, 0.f, 0.f, 0.f);

    if (tid < NROWS) {
        int deg = 0;
#pragma unroll
        for (int d = 0; d < ND; ++d)
            deg += (edges[tid * ND + d] != -1) ? 1 : 0;
        if (deg < ND) {
            int idx = atomicAdd(&cnt[deg], 1);
            lists[deg * NROWS + idx] = tid;
        }
    }
}

__global__ __launch_bounds__(256) void matvec(
    const float* __restrict__ atoms,   // NROWS*NFA
    const float* __restrict__ bonds,   // NROWS*ND*NFB
    const int*   __restrict__ edges,   // NROWS*ND
    const float* __restrict__ W,       // ND*NF*NC
    const float* __restrict__ bias,    // ND*NC
    const int*   __restrict__ cnt,
    const int*   __restrict__ lists,
    float* __restrict__ out)           // NROWS*NC
{
    __shared__ int   rows_s[GROUP];
    __shared__ float feat[GROUP][NF];  // 8*320*4 = 10 KB; rows 16B-aligned

    const int t = threadIdx.x;         // channel

    // tile layout over per-deg lists (uniform scalar computation)
    int pre[ND + 1];
    pre[0] = 0;
#pragma unroll
    for (int d = 0; d < ND; ++d)
        pre[d + 1] = pre[d] + (cnt[d] + GROUP - 1) / GROUP;
    const int total_tiles = pre[ND];

    for (int tile = blockIdx.x; tile < total_tiles; tile += gridDim.x) {
        int d = 0;
        while (tile >= pre[d + 1]) ++d;          // block-uniform
        const int base = (tile - pre[d]) * GROUP;
        const int n = min(GROUP, cnt[d] - base);

        __syncthreads();                         // protect LDS reuse
        if (t < GROUP)
            rows_s[t] = (t < n) ? lists[d * NROWS + base + t] : -1;
        __syncthreads();

        // build feat[r][0..319] for the 8 rows
#pragma unroll
        for (int r = 0; r < GROUP; ++r) {
            const int row = rows_s[r];
            if (row < 0) continue;               // block-uniform branch
            const int b = row >> 7;
            float v = atoms[(size_t)row * NFA + t];
#pragma unroll
            for (int dd = 0; dd < ND; ++dd) {
                const int e = edges[row * ND + dd];
                if (e != -1)
                    v += atoms[((size_t)(b * NA + e)) * NFA + t];
            }
            feat[r][t] = v;
            if (t < NFB) {
                float s = 0.f;
#pragma unroll
                for (int dd = 0; dd < ND; ++dd)
                    s += bonds[(size_t)row * (ND * NFB) + dd * NFB + t];
                feat[r][NFA + t] = s;
            }
        }
        __syncthreads();

        // acc over 8 rows; thread t = output channel t; W streamed once
        float acc[GROUP];
        const float bv = bias[d * NC + t];
#pragma unroll
        for (int r = 0; r < GROUP; ++r) acc[r] = bv;

        const float* Wd = W + (size_t)d * NF * NC + t;
        for (int f = 0; f < NF; f += 4) {
            const float w0 = Wd[(size_t)(f + 0) * NC];
            const float w1 = Wd[(size_t)(f + 1) * NC];
            const float w2 = Wd[(size_t)(f + 2) * NC];
            const float w3 = Wd[(size_t)(f + 3) * NC];
#pragma unroll
            for (int r = 0; r < GROUP; ++r) {
                const float4 fe = *(const float4*)&feat[r][f];  // LDS broadcast
                acc[r] = fmaf(fe.x, w0,
                         fmaf(fe.y, w1,
                         fmaf(fe.z, w2,
                         fmaf(fe.w, w3, acc[r]))));
            }
        }

#pragma unroll
        for (int r = 0; r < GROUP; ++r) {
            const int row = rows_s[r];
            if (row >= 0)
                out[(size_t)row * NC + t] = fmaxf(acc[r], 0.f);
        }
    }
}

extern "C" void kernel_launch(void* const* d_in, const int* in_sizes, int n_in,
                              void* d_out, int out_size, void* d_ws, size_t ws_size,
                              hipStream_t stream) {
    const float* atoms = (const float*)d_in[0];
    const float* bonds = (const float*)d_in[1];
    const int*   edges = (const int*)  d_in[2];
    const float* W     = (const float*)d_in[3];
    const float* bias  = (const float*)d_in[4];
    float*       out   = (float*)d_out;

    int* cnt   = (int*)d_ws;           // 8 ints
    int* lists = (int*)d_ws + 8;       // 5*NROWS ints (~640 KB)

    hipMemsetAsync(cnt, 0, 8 * sizeof(int), stream);
    classify_zero<<<256, 256, 0, stream>>>(edges, (float4*)out, cnt, lists);
    matvec<<<256, 256, 0, stream>>>(atoms, bonds, edges, W, bias, cnt, lists, out);
}

// Round 3
// 142.623 us; speedup vs baseline: 1.0754x; 1.0754x over previous
//
#include <hip/hip_runtime.h>

// B=256, A=128, D=5, FA=256, FB=64, C=256, F=320.
// deg==5 (~96% of rows) -> exact-zero output row; only ~1300 heavy rows need
// relu(feat(320) @ W[deg](320x256) + b[deg]).
//
// ONE dispatch, one block per batch b (256 blocks = 1 block/CU):
//   A) stage edges in LDS, compute deg, build per-deg row lists (LDS atomics)
//   B) zero-fill deg==5 rows (float4, wave-uniform skip per row)
//   C) heavy rows in groups of 8: build feat in LDS, then each wave computes
//      ALL 256 channels (4/thread) for 2 rows -> each row's feat is LDS-
//      broadcast to exactly ONE wave (min LDS return-bus traffic), and the
//      4 waves share the W[d] stream via L1 (one 320KB stream per block).

#define ND 5
#define NA 128
#define NFA 256
#define NFB 64
#define NC 256
#define NF 320
#define GROUP 8

__global__ __launch_bounds__(256, 1) void ngh_fused(
    const float* __restrict__ atoms,   // B*A*FA
    const float* __restrict__ bonds,   // B*A*D*FB
    const int*   __restrict__ edges,   // B*A*D
    const float* __restrict__ W,       // D*F*C
    const float* __restrict__ bias,    // D*C
    float* __restrict__ out)           // B*A*C
{
    const int b    = blockIdx.x;       // batch index
    const int t    = threadIdx.x;
    const int lane = t & 63;
    const int wv   = t >> 6;

    __shared__ int   edges_s[NA * ND];   // 2.5 KB
    __shared__ int   deg_s[NA];
    __shared__ int   hlist[ND][NA];      // 2.5 KB (cap = full block, no overflow)
    __shared__ int   hcnt[ND];
    __shared__ float feat[GROUP][NF];    // 10 KB

    if (t < ND) hcnt[t] = 0;
    for (int i = t; i < NA * ND; i += 256)
        edges_s[i] = edges[b * (NA * ND) + i];
    __syncthreads();

    if (t < NA) {
        int deg = 0;
#pragma unroll
        for (int dd = 0; dd < ND; ++dd)
            deg += (edges_s[t * ND + dd] != -1) ? 1 : 0;
        deg_s[t] = deg;
        if (deg < ND) {
            int idx = atomicAdd(&hcnt[deg], 1);
            hlist[deg][idx] = t;
        }
    }
    __syncthreads();

    // Phase B: zero-fill deg==5 rows. Each wave-iteration covers exactly one
    // row (64 float4 = 1 row), so the skip branch is wave-uniform.
    {
        float4* out4 = (float4*)out + (size_t)b * (NA * NC / 4);
        for (int i = t; i < NA * NC / 4; i += 256) {
            if (deg_s[i >> 6] == ND)
                out4[i] = make_float4(0.f, 0.f, 0.f, 0.f);
        }
    }

    // Phase C: heavy rows, grouped by deg (W stream shared per group).
    for (int d = 0; d < ND; ++d) {
        const int nd = hcnt[d];
        const float4* W4 = (const float4*)W + (size_t)d * (NF * NC / 4) + lane;
        for (int base = 0; base < nd; base += GROUP) {
            const int n = min(GROUP, nd - base);
            __syncthreads();             // protect feat from previous group
            for (int r = 0; r < n; ++r) {
                const int rl  = hlist[d][base + r];
                const int row = b * NA + rl;
                float v = atoms[(size_t)row * NFA + t];
#pragma unroll
                for (int dd = 0; dd < ND; ++dd) {
                    const int e = edges_s[rl * ND + dd];   // wave-uniform
                    if (e >= 0)
                        v += atoms[(size_t)(b * NA + e) * NFA + t];
                }
                feat[r][t] = v;
                if (t < NFB) {
                    float s = 0.f;
#pragma unroll
                    for (int dd = 0; dd < ND; ++dd)
                        s += bonds[((size_t)row * ND + dd) * NFB + t];
                    feat[r][NFA + t] = s;
                }
            }
            __syncthreads();

            // wave wv -> rows (wv) and (wv+4); channels 4*lane..4*lane+3
            const int r0 = wv, r1 = wv + 4;
            const float4 bv = ((const float4*)bias)[d * (NC / 4) + lane];
            float4* out4 = (float4*)out + (size_t)b * (NA * NC / 4) + lane;

            if (r1 < n) {               // two rows share one W stream
                const float4* f0 = (const float4*)feat[r0];
                const float4* f1 = (const float4*)feat[r1];
                float4 a0 = bv, a1 = bv;
#pragma unroll 4
                for (int fc = 0; fc < NF / 4; ++fc) {
                    const float4 e0 = f0[fc];              // LDS broadcast
                    const float4 e1 = f1[fc];
#pragma unroll
                    for (int j = 0; j < 4; ++j) {
                        const float4 w = W4[(fc * 4 + j) * (NC / 4)];
                        const float s0 = j == 0 ? e0.x : j == 1 ? e0.y : j == 2 ? e0.z : e0.w;
                        const float s1 = j == 0 ? e1.x : j == 1 ? e1.y : j == 2 ? e1.z : e1.w;
                        a0.x = fmaf(s0, w.x, a0.x); a0.y = fmaf(s0, w.y, a0.y);
                        a0.z = fmaf(s0, w.z, a0.z); a0.w = fmaf(s0, w.w, a0.w);
                        a1.x = fmaf(s1, w.x, a1.x); a1.y = fmaf(s1, w.y, a1.y);
                        a1.z = fmaf(s1, w.z, a1.z); a1.w = fmaf(s1, w.w, a1.w);
                    }
                }
                const int rowl0 = hlist[d][base + r0];
                const int rowl1 = hlist[d][base + r1];
                out4[(size_t)rowl0 * (NC / 4)] =
                    make_float4(fmaxf(a0.x, 0.f), fmaxf(a0.y, 0.f),
                                fmaxf(a0.z, 0.f), fmaxf(a0.w, 0.f));
                out4[(size_t)rowl1 * (NC / 4)] =
                    make_float4(fmaxf(a1.x, 0.f), fmaxf(a1.y, 0.f),
                                fmaxf(a1.z, 0.f), fmaxf(a1.w, 0.f));
            } else if (r0 < n) {        // single row
                const float4* f0 = (const float4*)feat[r0];
                float4 a0 = bv;
#pragma unroll 4
                for (int fc = 0; fc < NF / 4; ++fc) {
                    const float4 e0 = f0[fc];
#pragma unroll
                    for (int j = 0; j < 4; ++j) {
                        const float4 w = W4[(fc * 4 + j) * (NC / 4)];
                        const float s0 = j == 0 ? e0.x : j == 1 ? e0.y : j == 2 ? e0.z : e0.w;
                        a0.x = fmaf(s0, w.x, a0.x); a0.y = fmaf(s0, w.y, a0.y);
                        a0.z = fmaf(s0, w.z, a0.z); a0.w = fmaf(s0, w.w, a0.w);
                    }
                }
                const int rowl0 = hlist[d][base + r0];
                out4[(size_t)rowl0 * (NC / 4)] =
                    make_float4(fmaxf(a0.x, 0.f), fmaxf(a0.y, 0.f),
                                fmaxf(a0.z, 0.f), fmaxf(a0.w, 0.f));
            }
        }
    }
}

extern "C" void kernel_launch(void* const* d_in, const int* in_sizes, int n_in,
                              void* d_out, int out_size, void* d_ws, size_t ws_size,
                              hipStream_t stream) {
    const float* atoms = (const float*)d_in[0];
    const float* bonds = (const float*)d_in[1];
    const int*   edges = (const int*)  d_in[2];
    const float* W     = (const float*)d_in[3];
    const float* bias  = (const float*)d_in[4];
    float*       out   = (float*)d_out;

    ngh_fused<<<256, 256, 0, stream>>>(atoms, bonds, edges, W, bias, out);
}

// Round 5
// 137.537 us; speedup vs baseline: 1.1152x; 1.0370x over previous
//
#include <hip/hip_runtime.h>

// B=256, A=128, D=5, FA=256, FB=64, C=256, F=320.
// mask=(deg==arange(5)): deg==5 (~96% of rows) -> exact-zero output row.
// Heavy rows (~1300) need relu(feat(320) @ W[deg](320x256) + b[deg]).
//
// R5: fully deterministic single dispatch (R4 failed post-timing replay with
// a missing heavy-row write; its only nondeterminism was the LDS atomic
// worklist -> eliminated here).
//   2048 blocks x 256 threads, 16 consecutive rows per block.
//   A) stage 16x5 edges -> LDS, compute deg_s (the only 2 barriers)
//   B) zero-fill deg==5 rows, float4, wave-uniform predicate
//   C) heavy rows assigned by deterministic scan: heavy_index%4 == wave.
//      Each wave independent: feat in REGISTERS (4 atom chunks + 1 bond
//      chunk per lane), broadcast via readlane (no LDS, no barriers, no
//      cross-thread races possible); W[d] streamed float4/lane; each row
//      written by exactly one wave.

#define ND 5
#define NA 128
#define NFA 256
#define NFB 64
#define NC 256
#define NF 320
#define RPB 16            // rows per block
#define NBLK 2048         // 32768 / RPB

__device__ __forceinline__ float bcast(float v, int l) {
    // wave-uniform lane index -> v_readlane_b32 (SGPR broadcast)
    return __int_as_float(__builtin_amdgcn_readlane(__float_as_int(v), l));
}

__global__ __launch_bounds__(256) void ngh_kernel(
    const float* __restrict__ atoms,   // B*A*FA
    const float* __restrict__ bonds,   // B*A*D*FB
    const int*   __restrict__ edges,   // B*A*D
    const float* __restrict__ W,       // D*F*C
    const float* __restrict__ bias,    // D*C
    float* __restrict__ out)           // B*A*C
{
    const int t     = threadIdx.x;
    const int lane  = t & 63;
    const int wv    = t >> 6;
    const int rbase = blockIdx.x * RPB;

    __shared__ int edges_s[RPB * ND];   // 320 B
    __shared__ int deg_s[RPB];

    if (t < RPB * ND) edges_s[t] = edges[rbase * ND + t];
    __syncthreads();

    if (t < RPB) {
        int deg = 0;
#pragma unroll
        for (int dd = 0; dd < ND; ++dd)
            deg += (edges_s[t * ND + dd] != -1) ? 1 : 0;
        deg_s[t] = deg;
    }
    __syncthreads();
    // After this point LDS is read-only -> no further barriers needed.

    // Phase B: zero-fill deg==5 rows. i>>6 = local row; 64 consecutive i
    // map to one row so the predicate is wave-uniform.
    {
        float4* out4 = (float4*)out + (size_t)rbase * (NC / 4);
#pragma unroll
        for (int k = 0; k < RPB * (NC / 4) / 256; ++k) {   // 4 iterations
            const int i = t + 256 * k;
            if (deg_s[i >> 6] == ND)
                out4[i] = make_float4(0.f, 0.f, 0.f, 0.f);
        }
    }

    // Phase C: heavy rows, one WAVE per row, deterministic round-robin.
    int h = 0;
    for (int rl = 0; rl < RPB; ++rl) {
        const int d = deg_s[rl];
        if (d >= ND) continue;                // block-uniform
        if ((h++ & 3) != wv) continue;        // wave-uniform

        const int row = rbase + rl;
        const int bb  = row >> 7;             // row / NA

        const int e0 = edges_s[rl * ND + 0];
        const int e1 = edges_s[rl * ND + 1];
        const int e2 = edges_s[rl * ND + 2];
        const int e3 = edges_s[rl * ND + 3];
        const int e4 = edges_s[rl * ND + 4];

        // feat in registers: lane holds f = 64*j + lane (j=0..3) + bond f=256+lane
        const float* arow = atoms + (size_t)row * NFA;
        float f0 = arow[      lane];
        float f1 = arow[ 64 + lane];
        float f2 = arow[128 + lane];
        float f3 = arow[192 + lane];
#define ADD_NEIGH(E)                                                       \
        if ((E) >= 0) {                                                    \
            const float* nr = atoms + (size_t)(bb * NA + (E)) * NFA;       \
            f0 += nr[      lane];                                          \
            f1 += nr[ 64 + lane];                                          \
            f2 += nr[128 + lane];                                          \
            f3 += nr[192 + lane];                                          \
        }
        ADD_NEIGH(e0) ADD_NEIGH(e1) ADD_NEIGH(e2) ADD_NEIGH(e3) ADD_NEIGH(e4)
#undef ADD_NEIGH
        float fb = 0.f;
#pragma unroll
        for (int dd = 0; dd < ND; ++dd)
            fb += bonds[((size_t)row * ND + dd) * NFB + lane];

        // matvec: lane -> channels 4*lane..4*lane+3; f broadcast via readlane
        const float4* W4 = (const float4*)W + (size_t)d * NF * (NC / 4) + lane;
        float4 acc = ((const float4*)bias)[d * (NC / 4) + lane];

#define FMA_CHUNK(FREG, FBASE)                                             \
        _Pragma("unroll 16")                                               \
        for (int l = 0; l < 64; ++l) {                                     \
            const float  s = bcast((FREG), l);                             \
            const float4 w = W4[(size_t)((FBASE) + l) * (NC / 4)];         \
            acc.x = fmaf(s, w.x, acc.x);                                   \
            acc.y = fmaf(s, w.y, acc.y);                                   \
            acc.z = fmaf(s, w.z, acc.z);                                   \
            acc.w = fmaf(s, w.w, acc.w);                                   \
        }
        FMA_CHUNK(f0,   0)
        FMA_CHUNK(f1,  64)
        FMA_CHUNK(f2, 128)
        FMA_CHUNK(f3, 192)
        FMA_CHUNK(fb, 256)
#undef FMA_CHUNK

        ((float4*)out)[(size_t)row * (NC / 4) + lane] =
            make_float4(fmaxf(acc.x, 0.f), fmaxf(acc.y, 0.f),
                        fmaxf(acc.z, 0.f), fmaxf(acc.w, 0.f));
    }
}

extern "C" void kernel_launch(void* const* d_in, const int* in_sizes, int n_in,
                              void* d_out, int out_size, void* d_ws, size_t ws_size,
                              hipStream_t stream) {
    const float* atoms = (const float*)d_in[0];
    const float* bonds = (const float*)d_in[1];
    const int*   edges = (const int*)  d_in[2];
    const float* W     = (const float*)d_in[3];
    const float* bias  = (const float*)d_in[4];
    float*       out   = (float*)d_out;

    ngh_kernel<<<NBLK, 256, 0, stream>>>(atoms, bonds, edges, W, bias, out);
}

// Round 6
// 136.535 us; speedup vs baseline: 1.1234x; 1.0073x over previous
//
#include <hip/hip_runtime.h>

// B=256, A=128, D=5, FA=256, FB=64, C=256, F=320.
// mask=(deg==arange(5)): deg==5 (~96% of rows) -> exact-zero output row.
// Heavy rows (~1300) need relu(feat(320) @ W[deg](320x256) + b[deg]).
//
// R6: kill the per-row serial W stream (R1/R3/R5 all plateaued at ~44 us on
// a single wave's 320-load latency chain, made worse by the 32MB fill
// evicting W from L2):
//   - 4096 blocks x 256 thr, 8 rows/block, no atomics (deterministic).
//   - heavy rows FIRST, whole block per row: f-dim split 4 ways across
//     waves (80 W-loads per wave, ~4x shorter chain), LDS psum reduce,
//     parity double-buffered feat/psum -> 2 barriers per row.
//   - ALL output stores nontemporal -> the fill stream stops flushing W
//     out of each XCD's L2 (W is only 1.6 MB -> stays resident).

#define ND 5
#define NA 128
#define NFA 256
#define NFB 64
#define NC 256
#define NF 320
#define RPB 8
#define NBLK 4096          // 32768 / RPB

typedef float vf4 __attribute__((ext_vector_type(4)));

__global__ __launch_bounds__(256, 4) void ngh_kernel(
    const float* __restrict__ atoms,   // B*A*FA
    const float* __restrict__ bonds,   // B*A*D*FB
    const int*   __restrict__ edges,   // B*A*D
    const float* __restrict__ W,       // D*F*C
    const float* __restrict__ bias,    // D*C
    float* __restrict__ out)           // B*A*C
{
    const int t     = threadIdx.x;
    const int lane  = t & 63;
    const int wv    = t >> 6;
    const int rbase = blockIdx.x * RPB;

    __shared__ int   edges_s[RPB * ND];   // 160 B
    __shared__ int   deg_s[RPB];
    __shared__ float feat[2][NF];         // 2.5 KB (parity-buffered)
    __shared__ vf4   psum[2][3][64];      // 6 KB  (waves 1..3 publish)

    if (t < RPB * ND) edges_s[t] = edges[rbase * ND + t];
    __syncthreads();
    if (t < RPB) {
        int deg = 0;
#pragma unroll
        for (int dd = 0; dd < ND; ++dd)
            deg += (edges_s[t * ND + dd] != -1) ? 1 : 0;
        deg_s[t] = deg;
    }
    __syncthreads();

    // ---- Phase 1: heavy rows (block-cooperative, deterministic order) ----
    int p = 0;
    for (int rl = 0; rl < RPB; ++rl) {
        const int d = deg_s[rl];
        if (d >= ND) continue;            // block-uniform branch
        const int row = rbase + rl;
        const int bb  = row >> 7;         // row / NA

        // build feat[p][0..319]: thread t -> atom f=t; t<64 also bond f=256+t
        {
            float v = atoms[(size_t)row * NFA + t];
#pragma unroll
            for (int dd = 0; dd < ND; ++dd) {
                const int e = edges_s[rl * ND + dd];   // wave-uniform
                if (e >= 0)
                    v += atoms[(size_t)(bb * NA + e) * NFA + t];
            }
            feat[p][t] = v;
            if (t < NFB) {
                float s = 0.f;
#pragma unroll
                for (int dd = 0; dd < ND; ++dd)
                    s += bonds[((size_t)row * ND + dd) * NFB + t];
                feat[p][NFA + t] = s;
            }
        }
        __syncthreads();                  // barrier 1: feat ready

        // matvec: wave wv covers f in [80*wv, 80*wv+80), all 256 channels
        // (lane -> channels 4*lane..4*lane+3). 80 float4 W-loads per wave.
        const vf4* fseg = (const vf4*)(feat[p] + 80 * wv);   // 320B-aligned
        const vf4* W4   = (const vf4*)W +
                          ((size_t)d * NF + 80 * wv) * (NC / 4) + lane;
        vf4 a = {0.f, 0.f, 0.f, 0.f};
#pragma unroll 4
        for (int fc = 0; fc < 20; ++fc) {
            const vf4 fv = fseg[fc];                  // LDS broadcast b128
            const vf4 w0 = W4[(fc * 4 + 0) * 64];
            const vf4 w1 = W4[(fc * 4 + 1) * 64];
            const vf4 w2 = W4[(fc * 4 + 2) * 64];
            const vf4 w3 = W4[(fc * 4 + 3) * 64];
            a += fv.x * w0;               // contracts to v_fma_f32
            a += fv.y * w1;
            a += fv.z * w2;
            a += fv.w * w3;
        }
        if (wv > 0) psum[p][wv - 1][lane] = a;
        __syncthreads();                  // barrier 2: psums ready

        if (wv == 0) {
            vf4 r = a + psum[p][0][lane] + psum[p][1][lane] + psum[p][2][lane]
                      + ((const vf4*)bias)[d * (NC / 4) + lane];
            r.x = fmaxf(r.x, 0.f);
            r.y = fmaxf(r.y, 0.f);
            r.z = fmaxf(r.z, 0.f);
            r.w = fmaxf(r.w, 0.f);
            __builtin_nontemporal_store(
                r, (vf4*)out + (size_t)row * (NC / 4) + lane);
        }
        p ^= 1;   // parity buffers make an end-of-iteration barrier unneeded
    }

    // ---- Phase 2: zero-fill deg==5 rows (nontemporal, wave-uniform) ----
    {
        vf4* out4 = (vf4*)out + (size_t)rbase * (NC / 4);
        const vf4 z = {0.f, 0.f, 0.f, 0.f};
#pragma unroll
        for (int k = 0; k < RPB * (NC / 4) / 256; ++k) {   // 2 iterations
            const int i = t + 256 * k;
            if (deg_s[i >> 6] == ND)                       // wave-uniform
                __builtin_nontemporal_store(z, &out4[i]);
        }
    }
}

extern "C" void kernel_launch(void* const* d_in, const int* in_sizes, int n_in,
                              void* d_out, int out_size, void* d_ws, size_t ws_size,
                              hipStream_t stream) {
    const float* atoms = (const float*)d_in[0];
    const float* bonds = (const float*)d_in[1];
    const int*   edges = (const int*)  d_in[2];
    const float* W     = (const float*)d_in[3];
    const float* bias  = (const float*)d_in[4];
    float*       out   = (float*)d_out;

    ngh_kernel<<<NBLK, 256, 0, stream>>>(atoms, bonds, edges, W, bias, out);
}